// Round 6
// baseline (298.101 us; speedup 1.0000x reference)
//
#include <hip/hip_runtime.h>
#include <math.h>

// Problem constants (from reference setup): T=4, B=64, N=1024, P=63, D=128
#define T_STEPS 4
#define R_ROWS  65536              // B*N rows per timestep
#define M_ROWS  262144             // T*B*N total rows
#define P_DIM   63
#define D_DIM   128
#define PP      64                 // padded P (col 63 = virtual ones column in K1)

#define TILES_TOTAL (M_ROWS / 64)  // 4096 tiles of 64 rows
#define G_CHUNKS 8                 // reduce output copies consumed by stats

// ---------------------------------------------------------------------------
// K0: Wt[p*128+d] = W[d*63+p]  (coalesced writes; reads are a 32KB gather,
// L2-hot).  Removes the W transpose LDS round-trip from every lif block.
// ---------------------------------------------------------------------------
__global__ __launch_bounds__(256) void wt_kernel(const float* __restrict__ W,
                                                 float* __restrict__ Wt) {
    int j = blockIdx.x * 256 + threadIdx.x;
    if (j < P_DIM * D_DIM) {
        int p = j >> 7;
        int d = j & 127;
        Wt[j] = W[d * P_DIM + p];
    }
}

// ---------------------------------------------------------------------------
// K1: per-block partial Gram  P_b = xa_b^T xa_b  (xa = x + ones column).
// Double-buffered LDS staging (register prefetch), fp32 per 64-row tile ->
// fp64 per-block, PLAIN coalesced stores of the 64x64 fp64 partial.
// NO global atomics (round-2: fp64 atomics = ~32B HBM write each, L2 line
// ping-pong across XCDs serialized the kernel).
// ---------------------------------------------------------------------------
__global__ __launch_bounds__(256) void gram_kernel(const float* __restrict__ x,
                                                   double* __restrict__ partials,
                                                   int tiles_per_block) {
    __shared__ __align__(16) float xt[2][64 * PP];
    const int tid = threadIdx.x;
    const int tj = tid & 15;       // 16 col-tiles of 4
    const int ti = tid >> 4;       // 16 row-tiles of 4

    double dacc[4][4];
#pragma unroll
    for (int a = 0; a < 4; a++)
#pragma unroll
        for (int b = 0; b < 4; b++) dacc[a][b] = 0.0;

    if (tid < 64) {                // ones column in both buffers (never overwritten)
        xt[0][tid * PP + 63] = 1.0f;
        xt[1][tid * PP + 63] = 1.0f;
    }

    const int tile0 = blockIdx.x * tiles_per_block;
    float4 reg[4];

    // prefetch tile 0 -> regs
    {
        const float4* src = (const float4*)(x + (size_t)tile0 * (64 * 63));
#pragma unroll
        for (int it = 0; it < 4; it++) {
            int k = tid + it * 256;
            reg[it] = (k < 1008) ? src[k] : make_float4(0.f, 0.f, 0.f, 0.f);
        }
    }
#pragma unroll
    for (int it = 0; it < 4; it++) {
        int k = tid + it * 256;
        if (k < 1008) {
            const float* ve = (const float*)&reg[it];
            int flat = k * 4;
#pragma unroll
            for (int e = 0; e < 4; e++) {
                int f = flat + e;
                int r = f / 63;
                int c = f - r * 63;
                xt[0][r * PP + c] = ve[e];
            }
        }
    }
    __syncthreads();

    for (int t = 0; t < tiles_per_block; t++) {
        const int cur = t & 1;
        if (t + 1 < tiles_per_block) {
            const float4* src = (const float4*)(x + (size_t)(tile0 + t + 1) * (64 * 63));
#pragma unroll
            for (int it = 0; it < 4; it++) {
                int k = tid + it * 256;
                reg[it] = (k < 1008) ? src[k] : make_float4(0.f, 0.f, 0.f, 0.f);
            }
        }

        float facc[4][4];
#pragma unroll
        for (int a = 0; a < 4; a++)
#pragma unroll
            for (int b = 0; b < 4; b++) facc[a][b] = 0.0f;

        const float* buf = xt[cur];
        for (int r = 0; r < 64; r++) {
            float4 xi = *(const float4*)&buf[r * PP + ti * 4];
            float4 xj = *(const float4*)&buf[r * PP + tj * 4];
            const float* xia = (const float*)&xi;
            const float* xja = (const float*)&xj;
#pragma unroll
            for (int a = 0; a < 4; a++)
#pragma unroll
                for (int b = 0; b < 4; b++)
                    facc[a][b] = fmaf(xia[a], xja[b], facc[a][b]);
        }
#pragma unroll
        for (int a = 0; a < 4; a++)
#pragma unroll
            for (int b = 0; b < 4; b++) dacc[a][b] += (double)facc[a][b];

        __syncthreads();
        if (t + 1 < tiles_per_block) {
            float* nbuf = xt[1 - cur];
#pragma unroll
            for (int it = 0; it < 4; it++) {
                int k = tid + it * 256;
                if (k < 1008) {
                    const float* ve = (const float*)&reg[it];
                    int flat = k * 4;
#pragma unroll
                    for (int e = 0; e < 4; e++) {
                        int f = flat + e;
                        int r = f / 63;
                        int c = f - r * 63;
                        nbuf[r * PP + c] = ve[e];
                    }
                }
            }
            __syncthreads();
        }
    }

    double* Pb = partials + (size_t)blockIdx.x * 4096;
#pragma unroll
    for (int a = 0; a < 4; a++)
#pragma unroll
        for (int b = 0; b < 4; b++)
            Pb[(ti * 4 + a) * 64 + (tj * 4 + b)] = dacc[a][b];
}

// ---------------------------------------------------------------------------
// K1b: fold nparts partials into G_CHUNKS copies (deterministic fp64 sums).
// ---------------------------------------------------------------------------
__global__ __launch_bounds__(256) void reduce_kernel(const double* __restrict__ partials,
                                                     double* __restrict__ G8,
                                                     int copies_per_chunk) {
    const int chunk = blockIdx.x >> 4;             // 0..7
    const int idx   = (blockIdx.x & 15) * 256 + threadIdx.x;  // 0..4095
    const double* src = partials + (size_t)chunk * copies_per_chunk * 4096;
    double s = 0.0;
    for (int c = 0; c < copies_per_chunk; c++)
        s += src[(size_t)c * 4096 + idx];
    G8[(size_t)chunk * 4096 + idx] = s;
}

// ---------------------------------------------------------------------------
// K2: per-channel stats.  mean_d = (colsum . W_d)/M ; E[h^2]_d = W_d G W_d^T / M
// var = E[h^2] - mean^2 (fp64).  stats[d] = {mean, invstd, gamma, beta}.
// ---------------------------------------------------------------------------
__global__ __launch_bounds__(64) void stats_kernel(const double* __restrict__ G,
                                                   const float* __restrict__ W,
                                                   const float* __restrict__ gamma,
                                                   const float* __restrict__ beta,
                                                   float* __restrict__ stats) {
    const int d = blockIdx.x;    // 0..127
    const int p = threadIdx.x;   // 0..63
    __shared__ float sW[64];
    sW[p] = (p < P_DIM) ? W[d * P_DIM + p] : 0.0f;
    __syncthreads();

    double inner = 0.0;
#pragma unroll
    for (int c = 0; c < G_CHUNKS; c++) {
        const double* Gr = G + (size_t)c * (64 * 64) + p * 64;
        for (int q = 0; q < 64; q++) inner += Gr[q] * (double)sW[q];
    }

    double contrib = (double)sW[p] * inner;   // row 63 has w=0 -> no effect
    double ex2M = contrib;
#pragma unroll
    for (int off = 32; off > 0; off >>= 1) ex2M += __shfl_down(ex2M, off, 64);
    double meanM = __shfl(inner, 63, 64);     // ones-row dot W_d = colsum . W_d

    if (p == 0) {
        double mean = meanM / (double)M_ROWS;
        double ex2  = ex2M  / (double)M_ROWS;
        double var  = ex2 - mean * mean;
        float varf  = (float)var;
        float vpe   = varf + 1e-5f;                 // ref: fp32 var + fp32 eps
        float invstd = (float)(1.0 / sqrt((double)vpe));
        stats[d * 4 + 0] = (float)mean;
        stats[d * 4 + 1] = invstd;
        stats[d * 4 + 2] = gamma[d];
        stats[d * 4 + 3] = beta[d];
    }
}

// ---------------------------------------------------------------------------
// K3: on-the-fly GEMM + BN affine (ref op order) + 4-step LIF in registers.
// Round-6: keep the 8 rows x 8 ch tile (1.0 B LDS per lane-FMA) but restore
// 3 blocks/CU (12 waves; r5's 65KB -> 2 blocks/CU was latency-starved):
//   - sw holds ONE p-half (32 p x 128 d = 16KB); half 1 is prefetched into
//     4 float4 regs at kernel start and dumped to LDS at the mid-loop
//     barrier (no mid-loop global latency).
//   - sx: 32 rows x 4 t, stride 64, quad-XOR swizzle by row-pair (main-loop
//     reads conflict-free; staging scatter ~2-way, overlapped with latency).
//   LDS total = 49152 B -> 3 blocks/CU.
// Per-accumulator fmaf chain stays ascending-p (half A p=0..31, half B
// p=32..62) -> bitwise-identical to r3/r4/r5 -> spike decisions unchanged.
// ---------------------------------------------------------------------------
#define LIF_ROWS 32
__global__ __launch_bounds__(256, 3) void lif_kernel(const float* __restrict__ x,
                                                     const float* __restrict__ Wt,
                                                     const float* __restrict__ stats,
                                                     float* __restrict__ out) {
    __shared__ __align__(16) float sw[32 * D_DIM];              // 16384 B (one p-half)
    __shared__ __align__(16) float sx[T_STEPS * LIF_ROWS * 64]; // 32768 B
    const int tid = threadIdx.x;

    // stage half A (p=0..31) of Wt: flat float4 copy, conflict-free
    const float4* wt4 = (const float4*)Wt;
#pragma unroll
    for (int i = 0; i < 4; i++) {
        int k = tid + i * 256;                 // < 1024
        ((float4*)sw)[k] = wt4[k];
    }
    // prefetch half B (p=32..62: floats 4096..8063 = 992 float4) into regs
    float4 h1[4];
#pragma unroll
    for (int i = 0; i < 4; i++) {
        int k = tid + i * 256;
        h1[i] = (k < 992) ? wt4[1024 + k] : make_float4(0.f, 0.f, 0.f, 0.f);
    }

    // stage x with quad-XOR swizzle (cs quad = c-quad ^ row-pair)
    const int r0 = blockIdx.x * LIF_ROWS;
    const int seg = tid >> 6;      // timestep 0..3
    const int lane = tid & 63;
    const float4* src = (const float4*)(x + ((size_t)seg * R_ROWS + r0) * P_DIM);
    for (int k = lane; k < 504; k += 64) {        // 32 rows x 63 = 504 float4
        float4 v = src[k];
        const float* ve = (const float*)&v;
        int flat = k * 4;
#pragma unroll
        for (int e = 0; e < 4; e++) {
            int f = flat + e;
            int r = f / 63;
            int c = f - r * 63;
            int cs = (((c >> 2) ^ ((r >> 1) & 3)) << 2) | (c & 3);
            sx[(seg * LIF_ROWS + r) * 64 + cs] = ve[e];
        }
    }
    __syncthreads();

    const int td = tid & 15;      // 16 channel-tiles of 8
    const int tr = tid >> 4;      // 16 row-pairs
    const int d0 = td * 8;
    const int lr0 = tr * 2;       // local rows lr0, lr0+1
    const int sq0 = (lr0 >> 1) & 3;   // swizzle class (same for i=0,1)

    float acc[T_STEPS][2][8];
#pragma unroll
    for (int t = 0; t < T_STEPS; t++)
#pragma unroll
        for (int i = 0; i < 2; i++)
#pragma unroll
            for (int j = 0; j < 8; j++) acc[t][i][j] = 0.0f;

    // ---- half A: pq = 0..7 (p = 0..31)
    for (int pq = 0; pq < 8; pq++) {
        const int p0 = pq * 4;                 // local == global p here
        float4 w[4][2];
#pragma unroll
        for (int pp = 0; pp < 4; pp++)
#pragma unroll
            for (int h = 0; h < 2; h++)
                w[pp][h] = *(const float4*)&sw[(p0 + pp) * D_DIM + d0 + h * 4];

        const int xq = (pq ^ sq0) << 2;
#pragma unroll
        for (int t = 0; t < T_STEPS; t++)
#pragma unroll
            for (int i = 0; i < 2; i++) {
                float4 xv = *(const float4*)&sx[(t * LIF_ROWS + lr0 + i) * 64 + xq];
                const float xe[4] = {xv.x, xv.y, xv.z, xv.w};
                float* a = acc[t][i];
#pragma unroll
                for (int pp = 0; pp < 4; pp++)
#pragma unroll
                    for (int h = 0; h < 2; h++) {
                        const float4 ww = w[pp][h];
                        a[h * 4 + 0] = fmaf(xe[pp], ww.x, a[h * 4 + 0]);
                        a[h * 4 + 1] = fmaf(xe[pp], ww.y, a[h * 4 + 1]);
                        a[h * 4 + 2] = fmaf(xe[pp], ww.z, a[h * 4 + 2]);
                        a[h * 4 + 3] = fmaf(xe[pp], ww.w, a[h * 4 + 3]);
                    }
            }
    }

    // ---- swap in half B (p=32..62) from registers
    __syncthreads();
#pragma unroll
    for (int i = 0; i < 4; i++) {
        int k = tid + i * 256;
        if (k < 992) ((float4*)sw)[k] = h1[i];
    }
    __syncthreads();

    // ---- half B: pq = 8..14 (p = 32..59), local lp = p - 32
    for (int pq = 8; pq < 15; pq++) {
        const int lp0 = pq * 4 - 32;
        float4 w[4][2];
#pragma unroll
        for (int pp = 0; pp < 4; pp++)
#pragma unroll
            for (int h = 0; h < 2; h++)
                w[pp][h] = *(const float4*)&sw[(lp0 + pp) * D_DIM + d0 + h * 4];

        const int xq = (pq ^ sq0) << 2;
#pragma unroll
        for (int t = 0; t < T_STEPS; t++)
#pragma unroll
            for (int i = 0; i < 2; i++) {
                float4 xv = *(const float4*)&sx[(t * LIF_ROWS + lr0 + i) * 64 + xq];
                const float xe[4] = {xv.x, xv.y, xv.z, xv.w};
                float* a = acc[t][i];
#pragma unroll
                for (int pp = 0; pp < 4; pp++)
#pragma unroll
                    for (int h = 0; h < 2; h++) {
                        const float4 ww = w[pp][h];
                        a[h * 4 + 0] = fmaf(xe[pp], ww.x, a[h * 4 + 0]);
                        a[h * 4 + 1] = fmaf(xe[pp], ww.y, a[h * 4 + 1]);
                        a[h * 4 + 2] = fmaf(xe[pp], ww.z, a[h * 4 + 2]);
                        a[h * 4 + 3] = fmaf(xe[pp], ww.w, a[h * 4 + 3]);
                    }
            }
    }

    // tail: p = 60, 61, 62 (local 28..30, c-quad 15; same ascending order)
#pragma unroll
    for (int p = 60; p < 63; p++) {
        const int lp = p - 32;
        float4 wA = *(const float4*)&sw[lp * D_DIM + d0];
        float4 wB = *(const float4*)&sw[lp * D_DIM + d0 + 4];
        const int cs = ((15 ^ sq0) << 2) | (p & 3);
#pragma unroll
        for (int t = 0; t < T_STEPS; t++)
#pragma unroll
            for (int i = 0; i < 2; i++) {
                float xv = sx[(t * LIF_ROWS + lr0 + i) * 64 + cs];
                float* a = acc[t][i];
                a[0] = fmaf(xv, wA.x, a[0]);
                a[1] = fmaf(xv, wA.y, a[1]);
                a[2] = fmaf(xv, wA.z, a[2]);
                a[3] = fmaf(xv, wA.w, a[3]);
                a[4] = fmaf(xv, wB.x, a[4]);
                a[5] = fmaf(xv, wB.y, a[5]);
                a[6] = fmaf(xv, wB.z, a[6]);
                a[7] = fmaf(xv, wB.w, a[7]);
            }
    }

    // epilogue: BN affine (ref op order) + LIF scan; vectorized stores
#pragma unroll
    for (int i = 0; i < 2; i++) {
        const int row = r0 + lr0 + i;
        float sval[T_STEPS][8];
#pragma unroll
        for (int j = 0; j < 8; j++) {
            float4 st = ((const float4*)stats)[d0 + j];  // mean, invstd, gamma, beta
            float v = 0.0f;
#pragma unroll
            for (int t = 0; t < T_STEPS; t++) {
                float hn = (acc[t][i][j] - st.x) * st.y;
                hn = hn * st.z;
                hn = hn + st.w;
                v = v + (hn - v) * 0.5f;       // == v + (x-v)/2, exact
                float s = (v >= 1.0f) ? 1.0f : 0.0f;  // (v-1>=0) sign-exact
                sval[t][j] = s;
                if (s != 0.0f) v = 0.0f;       // hard reset
            }
        }
#pragma unroll
        for (int t = 0; t < T_STEPS; t++) {
            float* ob = &out[((size_t)t * R_ROWS + row) * D_DIM + d0];
            *(float4*)ob       = make_float4(sval[t][0], sval[t][1], sval[t][2], sval[t][3]);
            *(float4*)(ob + 4) = make_float4(sval[t][4], sval[t][5], sval[t][6], sval[t][7]);
        }
    }
}

// ---------------------------------------------------------------------------
extern "C" void kernel_launch(void* const* d_in, const int* in_sizes, int n_in,
                              void* d_out, int out_size, void* d_ws, size_t ws_size,
                              hipStream_t stream) {
    const float* x     = (const float*)d_in[0];
    const float* W     = (const float*)d_in[1];
    const float* gamma = (const float*)d_in[2];
    const float* beta  = (const float*)d_in[3];
    float* out = (float*)d_out;

    // fixed tail: G8 (256KB) + stats (2KB) + Wt (32.25KB) + pad
    const size_t fixed = (size_t)G_CHUNKS * 4096 * 8 + 2048 + 32768 + 4096;
    int nparts = 512;
    while (nparts > 64 && (size_t)nparts * 4096 * 8 + fixed > ws_size) nparts >>= 1;
    const int tiles_per_block = TILES_TOTAL / nparts;

    double* partials = (double*)d_ws;
    double* G8       = (double*)((char*)d_ws + (size_t)nparts * 4096 * 8);
    float*  stats    = (float*)((char*)G8 + (size_t)G_CHUNKS * 4096 * 8);
    float*  Wt       = (float*)((char*)stats + 2048);

    wt_kernel<<<(P_DIM * D_DIM + 255) / 256, 256, 0, stream>>>(W, Wt);
    gram_kernel<<<nparts, 256, 0, stream>>>(x, partials, tiles_per_block);
    reduce_kernel<<<G_CHUNKS * 16, 256, 0, stream>>>(partials, G8, nparts / G_CHUNKS);
    stats_kernel<<<D_DIM, 64, 0, stream>>>(G8, W, gamma, beta, stats);
    lif_kernel<<<R_ROWS / LIF_ROWS, 256, 0, stream>>>(x, Wt, stats, out);
}

// Round 7
// 292.362 us; speedup vs baseline: 1.0196x; 1.0196x over previous
//
#include <hip/hip_runtime.h>
#include <math.h>

// Problem constants (from reference setup): T=4, B=64, N=1024, P=63, D=128
#define T_STEPS 4
#define R_ROWS  65536              // B*N rows per timestep
#define M_ROWS  262144             // T*B*N total rows
#define P_DIM   63
#define D_DIM   128
#define PP      64                 // padded P (col 63 = virtual ones column in K1)

#define TILES_TOTAL (M_ROWS / 64)  // 4096 tiles of 64 rows
#define G_CHUNKS 8                 // reduce output copies consumed by stats

typedef float v4f __attribute__((ext_vector_type(4)));

// ---------------------------------------------------------------------------
// K1: per-block partial Gram  P_b = xa_b^T xa_b  (xa = x + ones column).
// Double-buffered LDS staging (register prefetch), fp32 per 64-row tile ->
// fp64 per-block, PLAIN coalesced stores of the 64x64 fp64 partial.
// NO global atomics (round-2: fp64 atomics = ~32B HBM write each, L2 line
// ping-pong across XCDs serialized the kernel).
// ---------------------------------------------------------------------------
__global__ __launch_bounds__(256) void gram_kernel(const float* __restrict__ x,
                                                   double* __restrict__ partials,
                                                   int tiles_per_block) {
    __shared__ __align__(16) float xt[2][64 * PP];
    const int tid = threadIdx.x;
    const int tj = tid & 15;       // 16 col-tiles of 4
    const int ti = tid >> 4;       // 16 row-tiles of 4

    double dacc[4][4];
#pragma unroll
    for (int a = 0; a < 4; a++)
#pragma unroll
        for (int b = 0; b < 4; b++) dacc[a][b] = 0.0;

    if (tid < 64) {                // ones column in both buffers (never overwritten)
        xt[0][tid * PP + 63] = 1.0f;
        xt[1][tid * PP + 63] = 1.0f;
    }

    const int tile0 = blockIdx.x * tiles_per_block;
    float4 reg[4];

    // prefetch tile 0 -> regs
    {
        const float4* src = (const float4*)(x + (size_t)tile0 * (64 * 63));
#pragma unroll
        for (int it = 0; it < 4; it++) {
            int k = tid + it * 256;
            reg[it] = (k < 1008) ? src[k] : make_float4(0.f, 0.f, 0.f, 0.f);
        }
    }
#pragma unroll
    for (int it = 0; it < 4; it++) {
        int k = tid + it * 256;
        if (k < 1008) {
            const float* ve = (const float*)&reg[it];
            int flat = k * 4;
#pragma unroll
            for (int e = 0; e < 4; e++) {
                int f = flat + e;
                int r = f / 63;
                int c = f - r * 63;
                xt[0][r * PP + c] = ve[e];
            }
        }
    }
    __syncthreads();

    for (int t = 0; t < tiles_per_block; t++) {
        const int cur = t & 1;
        if (t + 1 < tiles_per_block) {
            const float4* src = (const float4*)(x + (size_t)(tile0 + t + 1) * (64 * 63));
#pragma unroll
            for (int it = 0; it < 4; it++) {
                int k = tid + it * 256;
                reg[it] = (k < 1008) ? src[k] : make_float4(0.f, 0.f, 0.f, 0.f);
            }
        }

        float facc[4][4];
#pragma unroll
        for (int a = 0; a < 4; a++)
#pragma unroll
            for (int b = 0; b < 4; b++) facc[a][b] = 0.0f;

        const float* buf = xt[cur];
        for (int r = 0; r < 64; r++) {
            float4 xi = *(const float4*)&buf[r * PP + ti * 4];
            float4 xj = *(const float4*)&buf[r * PP + tj * 4];
            const float* xia = (const float*)&xi;
            const float* xja = (const float*)&xj;
#pragma unroll
            for (int a = 0; a < 4; a++)
#pragma unroll
                for (int b = 0; b < 4; b++)
                    facc[a][b] = fmaf(xia[a], xja[b], facc[a][b]);
        }
#pragma unroll
        for (int a = 0; a < 4; a++)
#pragma unroll
            for (int b = 0; b < 4; b++) dacc[a][b] += (double)facc[a][b];

        __syncthreads();
        if (t + 1 < tiles_per_block) {
            float* nbuf = xt[1 - cur];
#pragma unroll
            for (int it = 0; it < 4; it++) {
                int k = tid + it * 256;
                if (k < 1008) {
                    const float* ve = (const float*)&reg[it];
                    int flat = k * 4;
#pragma unroll
                    for (int e = 0; e < 4; e++) {
                        int f = flat + e;
                        int r = f / 63;
                        int c = f - r * 63;
                        nbuf[r * PP + c] = ve[e];
                    }
                }
            }
            __syncthreads();
        }
    }

    double* Pb = partials + (size_t)blockIdx.x * 4096;
#pragma unroll
    for (int a = 0; a < 4; a++)
#pragma unroll
        for (int b = 0; b < 4; b++)
            Pb[(ti * 4 + a) * 64 + (tj * 4 + b)] = dacc[a][b];
}

// ---------------------------------------------------------------------------
// K1b: fold nparts partials into G_CHUNKS copies (deterministic fp64 sums).
// ---------------------------------------------------------------------------
__global__ __launch_bounds__(256) void reduce_kernel(const double* __restrict__ partials,
                                                     double* __restrict__ G8,
                                                     int copies_per_chunk) {
    const int chunk = blockIdx.x >> 4;             // 0..7
    const int idx   = (blockIdx.x & 15) * 256 + threadIdx.x;  // 0..4095
    const double* src = partials + (size_t)chunk * copies_per_chunk * 4096;
    double s = 0.0;
    for (int c = 0; c < copies_per_chunk; c++)
        s += src[(size_t)c * 4096 + idx];
    G8[(size_t)chunk * 4096 + idx] = s;
}

// ---------------------------------------------------------------------------
// K2: per-channel stats.  mean_d = (colsum . W_d)/M ; E[h^2]_d = W_d G W_d^T / M
// var = E[h^2] - mean^2 (fp64).  stats[d] = {mean, invstd, gamma, beta}.
// ---------------------------------------------------------------------------
__global__ __launch_bounds__(64) void stats_kernel(const double* __restrict__ G,
                                                   const float* __restrict__ W,
                                                   const float* __restrict__ gamma,
                                                   const float* __restrict__ beta,
                                                   float* __restrict__ stats) {
    const int d = blockIdx.x;    // 0..127
    const int p = threadIdx.x;   // 0..63
    __shared__ float sW[64];
    sW[p] = (p < P_DIM) ? W[d * P_DIM + p] : 0.0f;
    __syncthreads();

    double inner = 0.0;
#pragma unroll
    for (int c = 0; c < G_CHUNKS; c++) {
        const double* Gr = G + (size_t)c * (64 * 64) + p * 64;
        for (int q = 0; q < 64; q++) inner += Gr[q] * (double)sW[q];
    }

    double contrib = (double)sW[p] * inner;   // row 63 has w=0 -> no effect
    double ex2M = contrib;
#pragma unroll
    for (int off = 32; off > 0; off >>= 1) ex2M += __shfl_down(ex2M, off, 64);
    double meanM = __shfl(inner, 63, 64);     // ones-row dot W_d = colsum . W_d

    if (p == 0) {
        double mean = meanM / (double)M_ROWS;
        double ex2  = ex2M  / (double)M_ROWS;
        double var  = ex2 - mean * mean;
        float varf  = (float)var;
        float vpe   = varf + 1e-5f;                 // ref: fp32 var + fp32 eps
        float invstd = (float)(1.0 / sqrt((double)vpe));
        stats[d * 4 + 0] = (float)mean;
        stats[d * 4 + 1] = invstd;
        stats[d * 4 + 2] = gamma[d];
        stats[d * 4 + 3] = beta[d];
    }
}

// ---------------------------------------------------------------------------
// K3: on-the-fly GEMM + BN affine (ref op order) + 4-step LIF in registers.
// Round-7 = round-4 structure (the fastest known: 82.2 us) + NONTEMPORAL
// out stores and x loads.  Rationale: r3/r4/r6 have internal walls (LDS
// 58/58/43 us) differing 35% yet all measure ~82 us; r6 showed WRITE
// amplification 134->165 MB and hbm_gbps ~2-2.6 TB/s tracking duration.
// Theory: 134 MB streaming out-write thrashes per-XCD L2 against x fetch.
// nt stores stream past L2; nt x loads avoid polluting L2 (x dead after
// this kernel).  Values and fmaf order bitwise-identical to r3-r6.
// ---------------------------------------------------------------------------
#define LIF_ROWS 16
#define SW_STRIDE 132
#define SX_STRIDE 64
__global__ __launch_bounds__(256) void lif_kernel(const float* __restrict__ x,
                                                  const float* __restrict__ W,
                                                  const float* __restrict__ stats,
                                                  float* __restrict__ out) {
    __shared__ __align__(16) float sw[P_DIM * SW_STRIDE];            // 33.3 KB
    __shared__ __align__(16) float sx[T_STEPS * LIF_ROWS * SX_STRIDE]; // 16 KB
    const int tid = threadIdx.x;

    // stage W: sequential-k coalesced global reads; scatter-transpose into LDS
    for (int k = tid; k < P_DIM * D_DIM; k += 256) {
        int d = k / 63;
        int p = k - d * 63;
        sw[p * SW_STRIDE + d] = W[k];
    }

    // stage x: flat coalesced nontemporal float4 loads, scatter into stride-64
    const int r0 = blockIdx.x * LIF_ROWS;
    const int seg = tid >> 6;      // timestep
    const int lane = tid & 63;
    const v4f* src = (const v4f*)(x + ((size_t)seg * R_ROWS + r0) * P_DIM);
    for (int k = lane; k < 252; k += 64) {
        v4f v = __builtin_nontemporal_load(&src[k]);
        int flat = k * 4;
#pragma unroll
        for (int e = 0; e < 4; e++) {
            int f = flat + e;
            int r = f / 63;
            int c = f - r * 63;
            sx[(seg * LIF_ROWS + r) * SX_STRIDE + c] = v[e];
        }
    }
    __syncthreads();

    const int td = tid & 31;      // 32 channel-tiles of 4
    const int tr = tid >> 5;      // 8 row-pairs
    const int d0 = td * 4;
    const int rowa = tr * 2;

    float acc[8][4];              // [t*2+i][j]
#pragma unroll
    for (int u = 0; u < 8; u++)
#pragma unroll
        for (int j = 0; j < 4; j++) acc[u][j] = 0.0f;

    // main loop: 15 p-quads (p = 0..59)
    for (int pq = 0; pq < 15; pq++) {
        const int p = pq * 4;
        float4 w0 = *(const float4*)&sw[(p + 0) * SW_STRIDE + d0];
        float4 w1 = *(const float4*)&sw[(p + 1) * SW_STRIDE + d0];
        float4 w2 = *(const float4*)&sw[(p + 2) * SW_STRIDE + d0];
        float4 w3 = *(const float4*)&sw[(p + 3) * SW_STRIDE + d0];
#pragma unroll
        for (int t = 0; t < T_STEPS; t++)
#pragma unroll
            for (int i = 0; i < 2; i++) {
                float4 xv = *(const float4*)&sx[(t * LIF_ROWS + rowa + i) * SX_STRIDE + p];
                float* a = acc[t * 2 + i];
                a[0] = fmaf(xv.x, w0.x, a[0]);
                a[1] = fmaf(xv.x, w0.y, a[1]);
                a[2] = fmaf(xv.x, w0.z, a[2]);
                a[3] = fmaf(xv.x, w0.w, a[3]);
                a[0] = fmaf(xv.y, w1.x, a[0]);
                a[1] = fmaf(xv.y, w1.y, a[1]);
                a[2] = fmaf(xv.y, w1.z, a[2]);
                a[3] = fmaf(xv.y, w1.w, a[3]);
                a[0] = fmaf(xv.z, w2.x, a[0]);
                a[1] = fmaf(xv.z, w2.y, a[1]);
                a[2] = fmaf(xv.z, w2.z, a[2]);
                a[3] = fmaf(xv.z, w2.w, a[3]);
                a[0] = fmaf(xv.w, w3.x, a[0]);
                a[1] = fmaf(xv.w, w3.y, a[1]);
                a[2] = fmaf(xv.w, w3.z, a[2]);
                a[3] = fmaf(xv.w, w3.w, a[3]);
            }
    }
    // tail: p = 60, 61, 62 (same ascending order)
#pragma unroll
    for (int p = 60; p < 63; p++) {
        float4 w4 = *(const float4*)&sw[p * SW_STRIDE + d0];
#pragma unroll
        for (int t = 0; t < T_STEPS; t++)
#pragma unroll
            for (int i = 0; i < 2; i++) {
                float xv = sx[(t * LIF_ROWS + rowa + i) * SX_STRIDE + p];
                float* a = acc[t * 2 + i];
                a[0] = fmaf(xv, w4.x, a[0]);
                a[1] = fmaf(xv, w4.y, a[1]);
                a[2] = fmaf(xv, w4.z, a[2]);
                a[3] = fmaf(xv, w4.w, a[3]);
            }
    }

    // epilogue: BN affine (ref op order) + LIF scan; nontemporal b128 stores
#pragma unroll
    for (int i = 0; i < 2; i++) {
        const int row = r0 + rowa + i;
        float sval[T_STEPS][4];
#pragma unroll
        for (int j = 0; j < 4; j++) {
            float4 st = ((const float4*)stats)[d0 + j];  // mean, invstd, gamma, beta
            float v = 0.0f;
#pragma unroll
            for (int t = 0; t < T_STEPS; t++) {
                float hn = (acc[t * 2 + i][j] - st.x) * st.y;
                hn = hn * st.z;
                hn = hn + st.w;
                v = v + (hn - v) * 0.5f;       // == v + (x-v)/2, exact
                float s = (v >= 1.0f) ? 1.0f : 0.0f;  // (v-1>=0) sign-exact
                sval[t][j] = s;
                if (s != 0.0f) v = 0.0f;       // hard reset
            }
        }
#pragma unroll
        for (int t = 0; t < T_STEPS; t++) {
            v4f o = {sval[t][0], sval[t][1], sval[t][2], sval[t][3]};
            __builtin_nontemporal_store(
                o, (v4f*)&out[((size_t)t * R_ROWS + row) * D_DIM + d0]);
        }
    }
}

// ---------------------------------------------------------------------------
extern "C" void kernel_launch(void* const* d_in, const int* in_sizes, int n_in,
                              void* d_out, int out_size, void* d_ws, size_t ws_size,
                              hipStream_t stream) {
    const float* x     = (const float*)d_in[0];
    const float* W     = (const float*)d_in[1];
    const float* gamma = (const float*)d_in[2];
    const float* beta  = (const float*)d_in[3];
    float* out = (float*)d_out;

    // pick partial count by available workspace (power of 2, 64..512)
    const size_t fixed = (size_t)G_CHUNKS * 4096 * 8 + 4096;  // G8 + stats + pad
    int nparts = 512;
    while (nparts > 64 && (size_t)nparts * 4096 * 8 + fixed > ws_size) nparts >>= 1;
    const int tiles_per_block = TILES_TOTAL / nparts;

    double* partials = (double*)d_ws;
    double* G8       = (double*)((char*)d_ws + (size_t)nparts * 4096 * 8);
    float*  stats    = (float*)((char*)G8 + (size_t)G_CHUNKS * 4096 * 8);

    gram_kernel<<<nparts, 256, 0, stream>>>(x, partials, tiles_per_block);
    reduce_kernel<<<G_CHUNKS * 16, 256, 0, stream>>>(partials, G8, nparts / G_CHUNKS);
    stats_kernel<<<D_DIM, 64, 0, stream>>>(G8, W, gamma, beta, stats);
    lif_kernel<<<R_ROWS / LIF_ROWS, 256, 0, stream>>>(x, W, stats, out);
}

// Round 8
// 288.094 us; speedup vs baseline: 1.0347x; 1.0148x over previous
//
#include <hip/hip_runtime.h>
#include <math.h>

// Problem constants (from reference setup): T=4, B=64, N=1024, P=63, D=128
#define T_STEPS 4
#define R_ROWS  65536              // B*N rows per timestep
#define M_ROWS  262144             // T*B*N total rows
#define P_DIM   63
#define D_DIM   128
#define PP      64                 // padded P (col 63 = virtual ones column in K1)

#define TILES_TOTAL (M_ROWS / 64)  // 4096 tiles of 64 rows
#define G_CHUNKS 8                 // reduce output copies consumed by stats

typedef float v2f __attribute__((ext_vector_type(2)));
typedef float v4f __attribute__((ext_vector_type(4)));

// v_pk_fma_f32: two independent IEEE fp32 FMAs per instruction (VOP3P).
// op_sel broadcasts one 32-bit half of the w pair to both result lanes:
//   lo-result = fma(x.lo, w.sel, acc.lo) ; hi-result = fma(x.hi, w.sel, acc.hi)
__device__ __forceinline__ void pk_fma_wlo(v2f& acc, v2f x, v2f w) {
    // w.lo broadcast: op_sel[1]=0 (lo half <- lo), op_sel_hi[1]=0 (hi half <- lo)
    asm("v_pk_fma_f32 %0, %1, %2, %0 op_sel:[0,0,0] op_sel_hi:[1,0,1]"
        : "+v"(acc) : "v"(x), "v"(w));
}
__device__ __forceinline__ void pk_fma_whi(v2f& acc, v2f x, v2f w) {
    // w.hi broadcast: op_sel[1]=1, op_sel_hi[1]=1
    asm("v_pk_fma_f32 %0, %1, %2, %0 op_sel:[0,1,0] op_sel_hi:[1,1,1]"
        : "+v"(acc) : "v"(x), "v"(w));
}

// ---------------------------------------------------------------------------
// K1: per-block partial Gram  P_b = xa_b^T xa_b  (xa = x + ones column).
// Double-buffered LDS staging, fp32 per 64-row tile -> fp64 per-block, plain
// coalesced stores (no global atomics: r2 showed fp64 atomics ping-pong L2).
// ---------------------------------------------------------------------------
__global__ __launch_bounds__(256) void gram_kernel(const float* __restrict__ x,
                                                   double* __restrict__ partials,
                                                   int tiles_per_block) {
    __shared__ __align__(16) float xt[2][64 * PP];
    const int tid = threadIdx.x;
    const int tj = tid & 15;       // 16 col-tiles of 4
    const int ti = tid >> 4;       // 16 row-tiles of 4

    double dacc[4][4];
#pragma unroll
    for (int a = 0; a < 4; a++)
#pragma unroll
        for (int b = 0; b < 4; b++) dacc[a][b] = 0.0;

    if (tid < 64) {                // ones column in both buffers (never overwritten)
        xt[0][tid * PP + 63] = 1.0f;
        xt[1][tid * PP + 63] = 1.0f;
    }

    const int tile0 = blockIdx.x * tiles_per_block;
    float4 reg[4];

    {
        const float4* src = (const float4*)(x + (size_t)tile0 * (64 * 63));
#pragma unroll
        for (int it = 0; it < 4; it++) {
            int k = tid + it * 256;
            reg[it] = (k < 1008) ? src[k] : make_float4(0.f, 0.f, 0.f, 0.f);
        }
    }
#pragma unroll
    for (int it = 0; it < 4; it++) {
        int k = tid + it * 256;
        if (k < 1008) {
            const float* ve = (const float*)&reg[it];
            int flat = k * 4;
#pragma unroll
            for (int e = 0; e < 4; e++) {
                int f = flat + e;
                int r = f / 63;
                int c = f - r * 63;
                xt[0][r * PP + c] = ve[e];
            }
        }
    }
    __syncthreads();

    for (int t = 0; t < tiles_per_block; t++) {
        const int cur = t & 1;
        if (t + 1 < tiles_per_block) {
            const float4* src = (const float4*)(x + (size_t)(tile0 + t + 1) * (64 * 63));
#pragma unroll
            for (int it = 0; it < 4; it++) {
                int k = tid + it * 256;
                reg[it] = (k < 1008) ? src[k] : make_float4(0.f, 0.f, 0.f, 0.f);
            }
        }

        float facc[4][4];
#pragma unroll
        for (int a = 0; a < 4; a++)
#pragma unroll
            for (int b = 0; b < 4; b++) facc[a][b] = 0.0f;

        const float* buf = xt[cur];
        for (int r = 0; r < 64; r++) {
            float4 xi = *(const float4*)&buf[r * PP + ti * 4];
            float4 xj = *(const float4*)&buf[r * PP + tj * 4];
            const float* xia = (const float*)&xi;
            const float* xja = (const float*)&xj;
#pragma unroll
            for (int a = 0; a < 4; a++)
#pragma unroll
                for (int b = 0; b < 4; b++)
                    facc[a][b] = fmaf(xia[a], xja[b], facc[a][b]);
        }
#pragma unroll
        for (int a = 0; a < 4; a++)
#pragma unroll
            for (int b = 0; b < 4; b++) dacc[a][b] += (double)facc[a][b];

        __syncthreads();
        if (t + 1 < tiles_per_block) {
            float* nbuf = xt[1 - cur];
#pragma unroll
            for (int it = 0; it < 4; it++) {
                int k = tid + it * 256;
                if (k < 1008) {
                    const float* ve = (const float*)&reg[it];
                    int flat = k * 4;
#pragma unroll
                    for (int e = 0; e < 4; e++) {
                        int f = flat + e;
                        int r = f / 63;
                        int c = f - r * 63;
                        nbuf[r * PP + c] = ve[e];
                    }
                }
            }
            __syncthreads();
        }
    }

    double* Pb = partials + (size_t)blockIdx.x * 4096;
#pragma unroll
    for (int a = 0; a < 4; a++)
#pragma unroll
        for (int b = 0; b < 4; b++)
            Pb[(ti * 4 + a) * 64 + (tj * 4 + b)] = dacc[a][b];
}

// ---------------------------------------------------------------------------
// K1b: fold nparts partials into G_CHUNKS copies (deterministic fp64 sums).
// ---------------------------------------------------------------------------
__global__ __launch_bounds__(256) void reduce_kernel(const double* __restrict__ partials,
                                                     double* __restrict__ G8,
                                                     int copies_per_chunk) {
    const int chunk = blockIdx.x >> 4;             // 0..7
    const int idx   = (blockIdx.x & 15) * 256 + threadIdx.x;  // 0..4095
    const double* src = partials + (size_t)chunk * copies_per_chunk * 4096;
    double s = 0.0;
    for (int c = 0; c < copies_per_chunk; c++)
        s += src[(size_t)c * 4096 + idx];
    G8[(size_t)chunk * 4096 + idx] = s;
}

// ---------------------------------------------------------------------------
// K2: per-channel stats.  mean_d = (colsum . W_d)/M ; E[h^2]_d = W_d G W_d^T / M
// var = E[h^2] - mean^2 (fp64).  stats[d] = {mean, invstd, gamma, beta}.
// ---------------------------------------------------------------------------
__global__ __launch_bounds__(64) void stats_kernel(const double* __restrict__ G,
                                                   const float* __restrict__ W,
                                                   const float* __restrict__ gamma,
                                                   const float* __restrict__ beta,
                                                   float* __restrict__ stats) {
    const int d = blockIdx.x;    // 0..127
    const int p = threadIdx.x;   // 0..63
    __shared__ float sW[64];
    sW[p] = (p < P_DIM) ? W[d * P_DIM + p] : 0.0f;
    __syncthreads();

    double inner = 0.0;
#pragma unroll
    for (int c = 0; c < G_CHUNKS; c++) {
        const double* Gr = G + (size_t)c * (64 * 64) + p * 64;
        for (int q = 0; q < 64; q++) inner += Gr[q] * (double)sW[q];
    }

    double contrib = (double)sW[p] * inner;   // row 63 has w=0 -> no effect
    double ex2M = contrib;
#pragma unroll
    for (int off = 32; off > 0; off >>= 1) ex2M += __shfl_down(ex2M, off, 64);
    double meanM = __shfl(inner, 63, 64);     // ones-row dot W_d = colsum . W_d

    if (p == 0) {
        double mean = meanM / (double)M_ROWS;
        double ex2  = ex2M  / (double)M_ROWS;
        double var  = ex2 - mean * mean;
        float varf  = (float)var;
        float vpe   = varf + 1e-5f;                 // ref: fp32 var + fp32 eps
        float invstd = (float)(1.0 / sqrt((double)vpe));
        stats[d * 4 + 0] = (float)mean;
        stats[d * 4 + 1] = invstd;
        stats[d * 4 + 2] = gamma[d];
        stats[d * 4 + 3] = beta[d];
    }
}

// ---------------------------------------------------------------------------
// K3: on-the-fly GEMM + BN affine (ref op order) + 4-step LIF in registers.
// Round-8 = round-7 (nt loads/stores) with the inner loop rebuilt on
// v_pk_fma_f32: the two rows of a thread's row-pair live in (lo,hi) of each
// accumulator pair, halving FMA issue count (r3-r7 all pinned at ~82 us with
// VALUBusy*dur ~ 47-58 us => VALU/issue-bound).  x stored row-interleaved in
// LDS so one b128 read yields 2 p's of (row0,row1) pairs; w lo/hi broadcast
// via VOP3P op_sel (no extra movs).  Each pk lane is an IEEE fma; per-channel
// chains stay ascending-p => bitwise-identical accumulators.
// ---------------------------------------------------------------------------
#define LIF_ROWS 16
#define SW_STRIDE 132
__global__ __launch_bounds__(256) void lif_kernel(const float* __restrict__ x,
                                                  const float* __restrict__ W,
                                                  const float* __restrict__ stats,
                                                  float* __restrict__ out) {
    __shared__ __align__(16) float sw[P_DIM * SW_STRIDE];       // 33264 B
    __shared__ __align__(16) float sx[T_STEPS * 8 * 128];       // 16384 B
    const int tid = threadIdx.x;

    // stage W: sequential-k coalesced global reads; scatter-transpose into LDS
    for (int k = tid; k < P_DIM * D_DIM; k += 256) {
        int d = k / 63;
        int p = k - d * 63;
        sw[p * SW_STRIDE + d] = W[k];
    }

    // stage x: flat coalesced nontemporal float4 loads, scatter row-interleaved:
    // sx[((t*8 + rowpair)*64 + p)*2 + (row&1)]
    const int r0 = blockIdx.x * LIF_ROWS;
    const int seg = tid >> 6;      // timestep
    const int lane = tid & 63;
    const v4f* src = (const v4f*)(x + ((size_t)seg * R_ROWS + r0) * P_DIM);
    for (int k = lane; k < 252; k += 64) {
        v4f v = __builtin_nontemporal_load(&src[k]);
        int flat = k * 4;
#pragma unroll
        for (int e = 0; e < 4; e++) {
            int f = flat + e;
            int r = f / 63;
            int c = f - r * 63;
            sx[((seg * 8 + (r >> 1)) * 64 + c) * 2 + (r & 1)] = v[e];
        }
    }
    __syncthreads();

    const int td = tid & 31;      // 32 channel-tiles of 4
    const int tr = tid >> 5;      // 8 row-pairs
    const int d0 = td * 4;

    v2f acc2[T_STEPS][4];         // [t][j]: lo=row 2tr, hi=row 2tr+1, ch d0+j
#pragma unroll
    for (int t = 0; t < T_STEPS; t++)
#pragma unroll
        for (int j = 0; j < 4; j++) acc2[t][j] = (v2f){0.0f, 0.0f};

    // main loop: 15 p-quads (p = 0..59)
    for (int pq = 0; pq < 15; pq++) {
        const int p0 = pq * 4;
        v2f w01[4], w23[4];       // (w[p][d0],w[p][d0+1]) and (d0+2,d0+3)
#pragma unroll
        for (int pp = 0; pp < 4; pp++) {
            w01[pp] = *(const v2f*)&sw[(p0 + pp) * SW_STRIDE + d0];
            w23[pp] = *(const v2f*)&sw[(p0 + pp) * SW_STRIDE + d0 + 2];
        }
#pragma unroll
        for (int t = 0; t < T_STEPS; t++) {
            const int base = ((t * 8 + tr) * 64 + p0) * 2;
            v4f xa = *(const v4f*)&sx[base];       // p0, p0+1 row-pairs
            v4f xb = *(const v4f*)&sx[base + 4];   // p0+2, p0+3 row-pairs
            v2f xp[4];
            xp[0] = (v2f){xa.x, xa.y};
            xp[1] = (v2f){xa.z, xa.w};
            xp[2] = (v2f){xb.x, xb.y};
            xp[3] = (v2f){xb.z, xb.w};
#pragma unroll
            for (int pp = 0; pp < 4; pp++) {
                pk_fma_wlo(acc2[t][0], xp[pp], w01[pp]);
                pk_fma_whi(acc2[t][1], xp[pp], w01[pp]);
                pk_fma_wlo(acc2[t][2], xp[pp], w23[pp]);
                pk_fma_whi(acc2[t][3], xp[pp], w23[pp]);
            }
        }
    }
    // tail: p = 60, 61, 62 (same ascending order)
#pragma unroll
    for (int p = 60; p < 63; p++) {
        v2f w01 = *(const v2f*)&sw[p * SW_STRIDE + d0];
        v2f w23 = *(const v2f*)&sw[p * SW_STRIDE + d0 + 2];
#pragma unroll
        for (int t = 0; t < T_STEPS; t++) {
            v2f xp = *(const v2f*)&sx[((t * 8 + tr) * 64 + p) * 2];
            pk_fma_wlo(acc2[t][0], xp, w01);
            pk_fma_whi(acc2[t][1], xp, w01);
            pk_fma_wlo(acc2[t][2], xp, w23);
            pk_fma_whi(acc2[t][3], xp, w23);
        }
    }

    // epilogue: BN affine (ref op order) + LIF scan; nontemporal b128 stores
    const int rowa = tr * 2;
#pragma unroll
    for (int i = 0; i < 2; i++) {
        const int row = r0 + rowa + i;
        float sval[T_STEPS][4];
#pragma unroll
        for (int j = 0; j < 4; j++) {
            float4 st = ((const float4*)stats)[d0 + j];  // mean, invstd, gamma, beta
            float v = 0.0f;
#pragma unroll
            for (int t = 0; t < T_STEPS; t++) {
                float hn = (acc2[t][j][i] - st.x) * st.y;
                hn = hn * st.z;
                hn = hn + st.w;
                v = v + (hn - v) * 0.5f;       // == v + (x-v)/2, exact
                float s = (v >= 1.0f) ? 1.0f : 0.0f;  // (v-1>=0) sign-exact
                sval[t][j] = s;
                if (s != 0.0f) v = 0.0f;       // hard reset
            }
        }
#pragma unroll
        for (int t = 0; t < T_STEPS; t++) {
            v4f o = {sval[t][0], sval[t][1], sval[t][2], sval[t][3]};
            __builtin_nontemporal_store(
                o, (v4f*)&out[((size_t)t * R_ROWS + row) * D_DIM + d0]);
        }
    }
}

// ---------------------------------------------------------------------------
extern "C" void kernel_launch(void* const* d_in, const int* in_sizes, int n_in,
                              void* d_out, int out_size, void* d_ws, size_t ws_size,
                              hipStream_t stream) {
    const float* x     = (const float*)d_in[0];
    const float* W     = (const float*)d_in[1];
    const float* gamma = (const float*)d_in[2];
    const float* beta  = (const float*)d_in[3];
    float* out = (float*)d_out;

    // pick partial count by available workspace (power of 2, 64..512)
    const size_t fixed = (size_t)G_CHUNKS * 4096 * 8 + 4096;  // G8 + stats + pad
    int nparts = 512;
    while (nparts > 64 && (size_t)nparts * 4096 * 8 + fixed > ws_size) nparts >>= 1;
    const int tiles_per_block = TILES_TOTAL / nparts;

    double* partials = (double*)d_ws;
    double* G8       = (double*)((char*)d_ws + (size_t)nparts * 4096 * 8);
    float*  stats    = (float*)((char*)G8 + (size_t)G_CHUNKS * 4096 * 8);

    gram_kernel<<<nparts, 256, 0, stream>>>(x, partials, tiles_per_block);
    reduce_kernel<<<G_CHUNKS * 16, 256, 0, stream>>>(partials, G8, nparts / G_CHUNKS);
    stats_kernel<<<D_DIM, 64, 0, stream>>>(G8, W, gamma, beta, stats);
    lif_kernel<<<R_ROWS / LIF_ROWS, 256, 0, stream>>>(x, W, stats, out);
}